// Round 2
// baseline (375.007 us; speedup 1.0000x reference)
//
#include <hip/hip_runtime.h>

#define EPS 1e-8f
#define BM 256
#define BN 256
#define BK 32

typedef __attribute__((ext_vector_type(8))) short bf16x8;   // 8 bf16 = 4 VGPRs
typedef __attribute__((ext_vector_type(4))) float f32x4;    // MFMA C/D

// RNE float -> bf16 (inputs are finite normals; no NaN handling needed)
__device__ inline unsigned short f2bf(float f) {
    union { float f; unsigned u; } c; c.f = f;
    unsigned u = c.u;
    return (unsigned short)((u + 0x7fffu + ((u >> 16) & 1u)) >> 16);
}

// One wave per row: norms + bf16 conversion for BOTH inputs in one launch.
// Rows [0,M) = x2 -> Abf/nA ; rows [M, M+N) = x1 -> Bbf/nB.
__global__ void prep_kernel(const float* __restrict__ x1, const float* __restrict__ x2,
                            unsigned short* __restrict__ Abf, unsigned short* __restrict__ Bbf,
                            float* __restrict__ nA, float* __restrict__ nB,
                            int M, int N, int K) {
    const int r = blockIdx.x * 4 + (threadIdx.x >> 6);
    const int lane = threadIdx.x & 63;
    if (r >= M + N) return;
    const float* p;
    unsigned short* q;
    float* nrm;
    if (r < M) { p = x2 + (size_t)r * K; q = Abf + (size_t)r * K; nrm = nA + r; }
    else       { const int rr = r - M;
                 p = x1 + (size_t)rr * K; q = Bbf + (size_t)rr * K; nrm = nB + rr; }
    float ss = 0.f;
    for (int base = lane * 4; base < K; base += 256) {
        float4 v = *(const float4*)(p + base);
        ss += v.x * v.x + v.y * v.y + v.z * v.z + v.w * v.w;
        ushort4 o;
        o.x = f2bf(v.x); o.y = f2bf(v.y); o.z = f2bf(v.z); o.w = f2bf(v.w);
        *(ushort4*)(q + base) = o;
    }
#pragma unroll
    for (int off = 32; off > 0; off >>= 1) ss += __shfl_down(ss, off, 64);
    if (lane == 0) *nrm = sqrtf(ss);
}

#define GLOAD_LDS16(g, l)                                                         \
    __builtin_amdgcn_global_load_lds(                                             \
        (const __attribute__((address_space(1))) unsigned int*)(g),               \
        (__attribute__((address_space(3))) unsigned int*)(l), 16, 0, 0)

// 256x256 tile, BK=32, 16 waves (4M x 4N), double-buffered LDS (64 KiB),
// 4 waves/SIMD for implicit wave-level overlap (m114 regime). One barrier +
// one vmcnt(0) per K-tile; stage issued at tile TOP (issue-early, T14) so the
// drain at tile bottom is covered by this tile's ds_read+MFMA.
// LDS row = 32 bf16 = 64 B = 4 chunks of 16 B; chunk XOR-swizzled by ((row>>1)&3)
// (2 lanes per bank-group per quad -> conflict-free per m136).
// global_load_lds writes linearly; the per-lane GLOBAL source chunk is
// pre-swizzled with the same involution (rule #21).
__global__ __launch_bounds__(1024, 4) void gemm_cos_kernel(
    const unsigned short* __restrict__ A, const unsigned short* __restrict__ B,
    const float* __restrict__ nA, const float* __restrict__ nB,
    float* __restrict__ C, int M, int N, int K) {
    __shared__ __align__(16) unsigned short As[2][BM * BK];   // 2 x 16 KiB
    __shared__ __align__(16) unsigned short Bs[2][BN * BK];   // 2 x 16 KiB

    const int tid = threadIdx.x;
    const int w = tid >> 6;          // wave 0..15
    const int lane = tid & 63;
    const int wm = w >> 2;           // 0..3 : 64-row band of the M-tile
    const int wn = w & 3;            // 0..3 : 64-col band of the N-tile
    const int q = lane >> 4;         // quad (k-slice for A/B frags)
    const int l16 = lane & 15;

    // Bijective XCD-aware swizzle (gridDim.x % 8 == 0 enforced host-side)
    const int cpx = gridDim.x >> 3;
    const int bid = ((int)blockIdx.x & 7) * cpx + ((int)blockIdx.x >> 3);
    const int nbx = N / BN;
    const int by = bid / nbx, bx = bid - by * nbx;
    const int row0 = by * BM, col0 = bx * BN;

    // ---- staging geometry: one call covers a full 256x32 tile (16 waves x 1 KiB) ----
    // wave w writes LDS rows w*16 .. w*16+15 linearly; lane -> row w*16 + (lane>>2),
    // dest chunk = lane&3. Source chunk pre-swizzled: (lane&3) ^ ((lane>>3)&3).
    const int srow = (w << 4) + (lane >> 2);                 // 0..255
    const int schunk = (lane & 3) ^ ((lane >> 3) & 3);       // involution per row
    const unsigned short* gA = A + (size_t)(row0 + srow) * K + schunk * 8;
    const unsigned short* gB = B + (size_t)(col0 + srow) * K + schunk * 8;
    const int ldsoff = w * 512;                              // ushort offset (wave-uniform)

#define STAGE(b, t_) do {                                                        \
        GLOAD_LDS16(gA + (size_t)(t_) * BK, &As[(b)][ldsoff]);                   \
        GLOAD_LDS16(gB + (size_t)(t_) * BK, &Bs[(b)][ldsoff]);                   \
    } while (0)

    // ---- fragment-read geometry: chunk = q ^ ((row>>1)&3); row>>1 bits == l16>>1 ----
    const int koff = (q ^ ((l16 >> 1) & 3)) * 8;             // in ushort elements
    const int arow = wm * 64 + l16;                          // + m*16
    const int brow = wn * 64 + l16;                          // + n*16

    f32x4 acc[4][4] = {};

    // ---- prologue ----
    STAGE(0, 0);
    asm volatile("s_waitcnt vmcnt(0)" ::: "memory");
    __builtin_amdgcn_s_barrier();
    __builtin_amdgcn_sched_barrier(0);

    const int NT = K / BK;   // >= 2 enforced host-side
    for (int t = 0; t < NT; ++t) {
        const int buf = t & 1;
        // issue next tile's staging FIRST (latency hides under this tile's work)
        if (t + 1 < NT) STAGE(buf ^ 1, t + 1);

        const unsigned short* as_ = &As[buf][0];
        const unsigned short* bs_ = &Bs[buf][0];
        bf16x8 aF[4], bF[4];
#pragma unroll
        for (int m = 0; m < 4; ++m)
            aF[m] = *(const bf16x8*)(as_ + (arow + m * 16) * BK + koff);
#pragma unroll
        for (int n = 0; n < 4; ++n)
            bF[n] = *(const bf16x8*)(bs_ + (brow + n * 16) * BK + koff);

#pragma unroll
        for (int m = 0; m < 4; ++m)
#pragma unroll
            for (int n = 0; n < 4; ++n)
                acc[m][n] = __builtin_amdgcn_mfma_f32_16x16x32_bf16(
                    aF[m], bF[n], acc[m][n], 0, 0, 0);

        if (t + 1 < NT) {
            // own staged loads landed; barrier publishes them to all waves and
            // guarantees everyone finished reading buf before t+2 overwrites it
            asm volatile("s_waitcnt vmcnt(0)" ::: "memory");
            __builtin_amdgcn_sched_barrier(0);
            __builtin_amdgcn_s_barrier();
            __builtin_amdgcn_sched_barrier(0);
        }
    }

    // ---- epilogue: D[row=q*4+r][col=l16] per 16x16 tile (m89/m91-verified layout) ----
    const int crow0 = row0 + wm * 64 + q * 4;
    const int ccol0 = col0 + wn * 64 + l16;
    float rb[4];
#pragma unroll
    for (int n = 0; n < 4; ++n) rb[n] = nB[ccol0 + n * 16];
#pragma unroll
    for (int m = 0; m < 4; ++m) {
#pragma unroll
        for (int r = 0; r < 4; ++r) {
            const int row = crow0 + m * 16 + r;
            const float ra = nA[row];
            float* outp = C + (size_t)row * N + ccol0;
#pragma unroll
            for (int n = 0; n < 4; ++n) {
                float v = acc[m][n][r] / fmaxf(ra * rb[n], EPS);
                __builtin_nontemporal_store(v, outp + n * 16);   // C never re-read
            }
        }
    }
#undef STAGE
}

// Correctness-guard fallback (weird shapes / tiny ws): naive fp32.
__global__ void naive_kernel(const float* __restrict__ x1, const float* __restrict__ x2,
                             float* __restrict__ out, int N, int M, int K) {
    long long idx = (long long)blockIdx.x * blockDim.x + threadIdx.x;
    if (idx >= (long long)M * N) return;
    int m = (int)(idx / N), n = (int)(idx % N);
    const float* a = x2 + (size_t)m * K;
    const float* b = x1 + (size_t)n * K;
    float dot = 0.f, sa = 0.f, sb = 0.f;
    for (int k = 0; k < K; k++) {
        float av = a[k], bv = b[k];
        dot += av * bv; sa += av * av; sb += bv * bv;
    }
    out[idx] = dot / fmaxf(sqrtf(sa) * sqrtf(sb), EPS);
}

extern "C" void kernel_launch(void* const* d_in, const int* in_sizes, int n_in,
                              void* d_out, int out_size, void* d_ws, size_t ws_size,
                              hipStream_t stream) {
    const float* x1 = (const float*)d_in[0];   // [N][K]
    const float* x2 = (const float*)d_in[1];   // [M][K]
    float* out = (float*)d_out;                // [M][N]
    const int K = 512;
    const int N = in_sizes[0] / K;
    const int M = in_sizes[1] / K;

    const size_t szA = (size_t)M * K * sizeof(unsigned short);
    const size_t szB = (size_t)N * K * sizeof(unsigned short);
    const size_t need = szA + szB + (size_t)(M + N) * sizeof(float);

    const int nwg = (M / BM) * (N / BN);
    const bool fast = (in_sizes[0] % K == 0) && (in_sizes[1] % K == 0) &&
                      (M % BM == 0) && (N % BN == 0) && (K % BK == 0) && (K / BK >= 2) &&
                      (nwg % 8 == 0) &&
                      (need <= ws_size) && ((long long)M * N == (long long)out_size);

    if (fast) {
        unsigned short* Abf = (unsigned short*)d_ws;                       // x2 bf16
        unsigned short* Bbf = (unsigned short*)((char*)d_ws + szA);        // x1 bf16
        float* nA = (float*)((char*)d_ws + szA + szB);                     // ||x2[m]||
        float* nB = nA + M;                                                // ||x1[n]||
        prep_kernel<<<(M + N + 3) / 4, 256, 0, stream>>>(x1, x2, Abf, Bbf, nA, nB, M, N, K);
        gemm_cos_kernel<<<dim3(nwg), 1024, 0, stream>>>(Abf, Bbf, nA, nB, out, M, N, K);
    } else {
        long long total = (long long)M * N;
        int blocks = (int)((total + 255) / 256);
        naive_kernel<<<blocks, 256, 0, stream>>>(x1, x2, out, N, M, K);
    }
}